// Round 6
// baseline (138.506 us; speedup 1.0000x reference)
//
#include <hip/hip_runtime.h>
#include <stdint.h>

#define TT 64
#define BB 128
#define VV 4880
#define NF4R 1220                    // float4 per row (4880/4)
#define NROWS (TT * BB)              // 8192
#define TOTF4 (NROWS * NF4R)         // 9,994,240 float4-pairs
#define LOG_EPS_F 1e-8f
#define NBUCKET 64
#define NQ 9
#define THR0 0.992f                  // ~39 candidate elements/row expected
#define CAPR 96                      // per-row candidate key capacity
#define PCAPR 16                     // per-row positive-candidate capacity
#define LDSCAP 768                   // per-block staging capacity (exp ~156)
#define NTHREADS (2048u * 256u)      // phase-1 total threads

// full u64 key for rescan path: (value desc, idx asc) via single compare
__device__ __forceinline__ uint64_t mkkey64(float v, int idx) {
  return ((uint64_t)__float_as_uint(v) << 13) | (uint64_t)(8191 - idx);
}

__device__ __forceinline__ int lane_prefix(unsigned long long m) {
  return __builtin_amdgcn_mbcnt_hi((unsigned)(m >> 32),
         __builtin_amdgcn_mbcnt_lo((unsigned)m, 0));
}

// ---------------- phase 1: flat streaming scan ----------------
__global__ __launch_bounds__(256) void stream_kernel(
    const float* __restrict__ yhat, const float* __restrict__ yy,
    const float* __restrict__ length, float* __restrict__ bucket,
    uint32_t* __restrict__ cnt, uint32_t* __restrict__ pcnt,
    uint32_t* __restrict__ cand, uint32_t* __restrict__ pcand) {
  __shared__ float invlen_sh[BB];
  __shared__ uint64_t lbuf[LDSCAP];
  __shared__ int blkcnt;

  const int t = threadIdx.x;
  if (t < BB) invlen_sh[t] = 1.0f / length[t];
  if (t == 0) blkcnt = 0;
  __syncthreads();

  const unsigned gtid = blockIdx.x * 256u + t;
  const float4* h4 = (const float4*)yhat;
  const float4* y4 = (const float4*)yy;

  float ls = 0.0f;    // sum of log(selected) * inv_len
  float np = 0.0f;    // sum of y

  auto proc = [&](float4 h, float4 v, unsigned i) {
    // row = i / 1220 exactly (magic: 1220*112654880 = 2^37 + 128)
    unsigned row = (unsigned)(((uint64_t)i * 112654880ull) >> 37);
    float il = invlen_sh[row & (BB - 1)];
    float a0 = ((v.x != 0.0f) ? h.x : (1.0f - h.x)) + LOG_EPS_F;
    float a1 = ((v.y != 0.0f) ? h.y : (1.0f - h.y)) + LOG_EPS_F;
    float a2 = ((v.z != 0.0f) ? h.z : (1.0f - h.z)) + LOG_EPS_F;
    float a3 = ((v.w != 0.0f) ? h.w : (1.0f - h.w)) + LOG_EPS_F;
    ls = fmaf(__logf((a0 * a1) * (a2 * a3)), il, ls);  // product >= 1e-16
    np += (v.x + v.y) + (v.z + v.w);                   // y is exactly 0/1
    float hm = fmaxf(fmaxf(h.x, h.y), fmaxf(h.z, h.w));
    if (hm > THR0) {                                   // ~3% of float4s
      const unsigned base = (i - row * NF4R) * 4u;     // element idx in row
      const float hv[4] = {h.x, h.y, h.z, h.w};
      const float yv[4] = {v.x, v.y, v.z, v.w};
      #pragma unroll
      for (int e = 0; e < 4; ++e) {
        if (hv[e] > THR0) {
          // compact key: values in (0.992,1) span < 2^18 float-bit codes
          uint32_t key = ((__float_as_uint(hv[e]) - __float_as_uint(THR0)) << 13)
                         | (8191u - (base + e));
          uint32_t kp = key | ((yv[e] != 0.0f) ? 0x80000000u : 0u);
          int s = atomicAdd(&blkcnt, 1);
          if (s < LDSCAP) {
            lbuf[s] = ((uint64_t)row << 32) | kp;
          } else {  // overflow fallback: direct global (never in practice)
            uint32_t slot = atomicAdd(&cnt[row], 1u);
            if (slot < CAPR) cand[row * CAPR + slot] = key;
            if (kp >> 31) {
              uint32_t ps = atomicAdd(&pcnt[row], 1u);
              if (ps < PCAPR) pcand[row * PCAPR + ps] = key;
            }
          }
        }
      }
    }
  };

  // 2-way unrolled grid-stride loop (4 loads in flight, continuous issue)
  unsigned i = gtid;
  for (; i + NTHREADS < TOTF4; i += 2u * NTHREADS) {
    float4 ha = h4[i],            va = y4[i];
    float4 hb = h4[i + NTHREADS], vb = y4[i + NTHREADS];
    proc(ha, va, i);
    proc(hb, vb, i + NTHREADS);
  }
  if (i < TOTF4) proc(h4[i], y4[i], i);

  // per-wave reduce ce / n_pos, one atomic pair per wave
  #pragma unroll
  for (int sh = 32; sh >= 1; sh >>= 1) {
    ls += __shfl_xor(ls, sh, 64);
    np += __shfl_xor(np, sh, 64);
  }
  if ((t & 63) == 0) {
    float* bk = bucket + (size_t)((gtid >> 6) & (NBUCKET - 1)) * NQ;
    atomicAdd(bk + 0, -ls * (1.0f / (float)BB));   // cost partial
    atomicAdd(bk + 5, np);
    atomicAdd(bk + 6, np);
    atomicAdd(bk + 7, np);
    atomicAdd(bk + 8, np);
  }

  // flush block-staged candidates to per-row global lists
  __syncthreads();
  const int n = (blkcnt < LDSCAP) ? blkcnt : LDSCAP;
  for (int j = t; j < n; j += 256) {
    uint64_t u = lbuf[j];
    uint32_t row = (uint32_t)(u >> 32);
    uint32_t kp  = (uint32_t)u;
    uint32_t key = kp & 0x7FFFFFFFu;
    uint32_t slot = atomicAdd(&cnt[row], 1u);
    if (slot < CAPR) cand[row * CAPR + slot] = key;
    if (kp >> 31) {
      uint32_t ps = atomicAdd(&pcnt[row], 1u);
      if (ps < PCAPR) pcand[row * PCAPR + ps] = key;
    }
  }
}

// ---------------- phase 2: per-row ranking (tiny) ----------------
__global__ __launch_bounds__(64) void rank_kernel(
    const float* __restrict__ yhat, const float* __restrict__ yy,
    float* __restrict__ bucket,
    const uint32_t* __restrict__ cnt, const uint32_t* __restrict__ pcnt,
    const uint32_t* __restrict__ cand, const uint32_t* __restrict__ pcand) {
  __shared__ int fbuf[64];
  const int row  = blockIdx.x;
  const int lane = threadIdx.x;
  const uint32_t c  = cnt[row];
  const uint32_t pc = pcnt[row];

  float tpk[4] = {0.f, 0.f, 0.f, 0.f};
  bool have = false;

  if (c >= 20 && c <= CAPR && pc <= PCAPR) {
    if (pc > 0) {                       // ~32% of rows
      have = true;
      uint32_t k0 = (lane < (int)c) ? cand[row * CAPR + lane] : 0u;
      uint32_t k1 = (lane + 64 < (int)c) ? cand[row * CAPR + lane + 64] : 0u;
      for (int p = 0; p < (int)pc; ++p) {
        uint32_t pk = pcand[row * PCAPR + p];
        int cc = (k0 > pk) + (k1 > pk);
        #pragma unroll
        for (int sh = 32; sh >= 1; sh >>= 1) cc += __shfl_xor(cc, sh, 64);
        tpk[0] += (cc < 5);  tpk[1] += (cc < 10);
        tpk[2] += (cc < 15); tpk[3] += (cc < 20);
      }
    }
  } else {
    // ---- rescan path (expected ~3 rows/run) ----
    have = true;
    const float4* hr = (const float4*)(yhat + (size_t)row * VV);
    const float4* yr = (const float4*)(yy   + (size_t)row * VV);
    float thr = THR0;
    int lc = 0;
    auto scan = [&](float th) {
      int c2 = 0;
      for (int f = lane; f < NF4R; f += 64) {
        float4 h = hr[f];
        float hm = fmaxf(fmaxf(h.x, h.y), fmaxf(h.z, h.w));
        bool take = hm > th;
        unsigned long long m = __ballot(take);
        if (m) {
          if (take) { int s = c2 + lane_prefix(m); if (s < 64) fbuf[s] = f; }
          c2 += __popcll(m);
        }
      }
      return c2;
    };
    lc = scan(thr);
    int attempt = 0;
    while ((lc < 20 || lc > 64) && attempt < 10) {
      thr = (lc < 20) ? 1.0f - (1.0f - thr) * 2.5f
                      : 1.0f - (1.0f - thr) * 0.4f;
      lc = scan(thr);
      ++attempt;
    }
    const int tl = (lc < 64) ? lc : 64;
    const bool act = (lane < tl);
    const int f = act ? fbuf[lane] : 0;
    float4 h = hr[f], v = yr[f];
    uint64_t K0 = mkkey64(h.x, 4 * f),     K1 = mkkey64(h.y, 4 * f + 1);
    uint64_t K2 = mkkey64(h.z, 4 * f + 2), K3 = mkkey64(h.w, 4 * f + 3);
    const bool ve0 = act && (h.x > thr), ve1 = act && (h.y > thr);
    const bool ve2 = act && (h.z > thr), ve3 = act && (h.w > thr);
    int pmask = (ve0 && v.x != 0.0f) ? 1 : 0;
    pmask |= (ve1 && v.y != 0.0f) ? 2 : 0;
    pmask |= (ve2 && v.z != 0.0f) ? 4 : 0;
    pmask |= (ve3 && v.w != 0.0f) ? 8 : 0;
    unsigned long long pl = __ballot(pmask != 0);
    while (pl) {
      int s = __builtin_ctzll(pl);
      pl &= pl - 1;
      int flags = __shfl(pmask, s, 64);
      uint64_t pk0 = __shfl((unsigned long long)K0, s, 64);
      uint64_t pk1 = __shfl((unsigned long long)K1, s, 64);
      uint64_t pk2 = __shfl((unsigned long long)K2, s, 64);
      uint64_t pk3 = __shfl((unsigned long long)K3, s, 64);
      #pragma unroll
      for (int e = 0; e < 4; ++e) {
        if (flags & (1 << e)) {
          uint64_t pk = (e == 0) ? pk0 : (e == 1) ? pk1 : (e == 2) ? pk2 : pk3;
          int cc = (ve0 && K0 > pk) + (ve1 && K1 > pk) +
                   (ve2 && K2 > pk) + (ve3 && K3 > pk);
          #pragma unroll
          for (int sh = 32; sh >= 1; sh >>= 1) cc += __shfl_xor(cc, sh, 64);
          tpk[0] += (cc < 5);  tpk[1] += (cc < 10);
          tpk[2] += (cc < 15); tpk[3] += (cc < 20);
        }
      }
    }
  }

  if (have && lane == 0) {
    float* bk = bucket + (size_t)(row & (NBUCKET - 1)) * NQ;
    if (tpk[0] != 0.f) atomicAdd(bk + 1, tpk[0]);
    if (tpk[1] != 0.f) atomicAdd(bk + 2, tpk[1]);
    if (tpk[2] != 0.f) atomicAdd(bk + 3, tpk[2]);
    if (tpk[3] != 0.f) atomicAdd(bk + 4, tpk[3]);
  }
}

// ---------------- phase 3: bucket reduce ----------------
__global__ __launch_bounds__(64) void reduce_kernel(const float* __restrict__ bucket,
                                                    float* __restrict__ out) {
  const int lane = threadIdx.x;  // 64 lanes, one bucket each
  float acc[NQ];
  #pragma unroll
  for (int q = 0; q < NQ; ++q) acc[q] = bucket[lane * NQ + q];
  #pragma unroll
  for (int q = 0; q < NQ; ++q) {
    #pragma unroll
    for (int s = 32; s >= 1; s >>= 1) acc[q] += __shfl_xor(acc[q], s, 64);
  }
  if (lane == 0) {
    #pragma unroll
    for (int q = 0; q < NQ; ++q) out[q] = acc[q];
  }
}

extern "C" void kernel_launch(void* const* d_in, const int* in_sizes, int n_in,
                              void* d_out, int out_size, void* d_ws, size_t ws_size,
                              hipStream_t stream) {
  const float* yhat = (const float*)d_in[0];
  const float* yy   = (const float*)d_in[1];
  const float* len  = (const float*)d_in[2];
  float* out = (float*)d_out;

  uint8_t* ws = (uint8_t*)d_ws;
  float*    bucket = (float*)ws;                              // 2304 B (pad 4K)
  uint32_t* cnt    = (uint32_t*)(ws + 4096);                  // 32 KB
  uint32_t* pcnt   = (uint32_t*)(ws + 4096 + 32768);          // 32 KB
  uint32_t* pcand  = (uint32_t*)(ws + 4096 + 65536);          // 512 KB
  uint32_t* cand   = (uint32_t*)(ws + 4096 + 65536 + 524288); // 3 MB
  // total ws usage: ~3.65 MB

  hipMemsetAsync(ws, 0, 4096 + 65536, stream);  // bucket + cnt + pcnt
  stream_kernel<<<2048, 256, 0, stream>>>(yhat, yy, len, bucket, cnt, pcnt, cand, pcand);
  rank_kernel<<<NROWS, 64, 0, stream>>>(yhat, yy, bucket, cnt, pcnt, cand, pcand);
  reduce_kernel<<<1, 64, 0, stream>>>(bucket, out);
}